// Round 13
// baseline (665.448 us; speedup 1.0000x reference)
//
#include <hip/hip_runtime.h>

// Flux2 double-stream attention block, bf16 MFMA pipeline, f32 final output.
// Stages: cvt(f32->bf16) -> QKV GEMM (BK=32 4-buf fine-pipeline, 2-D XCD)
//         -> RMSnorm+RoPE(+V^T) -> flash attn (32x32, in-reg P) -> out GEMM.
// ws layout (bytes):
//   [0,           22020096)  A_in bf16 [3584][3072]   } later aliased by V^T [24][128][3584]
//   [22020096,   135266304)  Wq bf16: img [9216][3072] then enc } later aliased by attn_out
//   [135266304,  173015040)  Wo bf16: img [3072][3072] then enc
//   [173015040,  239075328)  qkv bf16 [3584][9216]
// peak ws = 239,075,328 B.

typedef unsigned short u16;
typedef __attribute__((ext_vector_type(2))) unsigned short u16x2;
typedef __attribute__((ext_vector_type(4))) unsigned short u16x4;
typedef __attribute__((ext_vector_type(8))) unsigned short u16x8;
typedef __attribute__((ext_vector_type(8))) short bf16x8;
typedef __attribute__((ext_vector_type(4))) float f32x4;
typedef __attribute__((ext_vector_type(16))) float f32x16;
typedef __attribute__((ext_vector_type(4))) unsigned u32x4;

#define DEV __device__ __forceinline__

DEV u16 f2bf(float f) {
  unsigned u = __builtin_bit_cast(unsigned, f);
  u = (u + 0x7FFFu + ((u >> 16) & 1u)) >> 16;   // RNE
  return (u16)u;
}
DEV float bf2f(u16 s) { return __builtin_bit_cast(float, (unsigned)s << 16); }

DEV void store_out(u16* p, float v)  { *p = f2bf(v); }
DEV void store_out(float* p, float v) { *p = v; }

#define AS1(p) (const __attribute__((address_space(1))) void*)(p)
#define AS3(p) (__attribute__((address_space(3))) void*)(p)
#define GLL16(g, l) __builtin_amdgcn_global_load_lds(AS1(g), AS3(l), 16, 0, 0)

// raw barrier (NOT __syncthreads: that emits s_waitcnt vmcnt(0) and drains the
// counted-vmcnt pipeline). Compiler-only memory fences pin op order around it.
#define BAR() do { asm volatile("" ::: "memory"); __builtin_amdgcn_s_barrier(); \
                   asm volatile("" ::: "memory"); } while (0)
#define VMC8() asm volatile("s_waitcnt vmcnt(8)" ::: "memory")
#define VMC4() asm volatile("s_waitcnt vmcnt(4)" ::: "memory")
#define VMC0() asm volatile("s_waitcnt vmcnt(0)" ::: "memory")

// ---------------- fp32 -> bf16 convert ----------------
__global__ __launch_bounds__(256) void cvt_kernel(const float* __restrict__ src,
                                                  u16* __restrict__ dst, int n4) {
  int i = blockIdx.x * blockDim.x + threadIdx.x;
  int stride = gridDim.x * blockDim.x;
  for (; i < n4; i += stride) {
    float4 v = reinterpret_cast<const float4*>(src)[i];
    u16x4 o;
    o.x = f2bf(v.x); o.y = f2bf(v.y); o.z = f2bf(v.z); o.w = f2bf(v.w);
    reinterpret_cast<u16x4*>(dst)[i] = o;
  }
}

// ---------------- GEMM (BK=32, 4-buf fine-pipeline, 256x256) ----------------
// C = A[M][K] * B[N][K]^T (+bias). 512 threads = 8 waves (2M x 4N), wave tile
// 128x64. Per 32-K tile (= one fine phase): {12 ds_read issue -> 4 stage-gll
// issue -> setprio -> 32 MFMA -> counted vmcnt -> 1 barrier}. 4 rotating LDS
// buffers (128 KiB): tile t reads buf t%4; tile t+3 staged into (t+3)%4 =
// (t-1)%4, dead for TWO barriers -> race-free. 3 tiles (12 glls) in flight;
// vmcnt(8) at tile end => t+1 landed (issued 3 tiles ~900cy earlier).
// Block-contiguous LDS (linear gll dest + per-lane source addr): unit u =
// 16-row group; byte = u*1024 + lane*16 holds X[16u+(lane&15)][k=(lane>>4)*8..]
// -> ds_read_b128 per MFMA frag, 64 consecutive slots = 0 bank conflicts.
// 2-D XCD chunk decode (R11-verified, FETCH 408->189 MB).
template <typename OT>
__global__ __launch_bounds__(512, 2) void gemm256(
    const u16* __restrict__ A,
    const u16* __restrict__ Bimg, const u16* __restrict__ Benc,
    const float* __restrict__ biasImg, const float* __restrict__ biasEnc,
    OT* __restrict__ Cimg, OT* __restrict__ Cenc,
    int N, int K, int split) {
  const int bid = blockIdx.x;
  const int ntn = N >> 8;
  const int CN = ntn >> 2;                 // nt per XCD band
  const int x = bid & 7, i5 = bid >> 3;    // XCD id, in-chunk index
  const int mt = (x >> 2) * 7 + i5 / CN;
  const int nt = (x & 3) * CN + i5 % CN;
  const int m0 = mt << 8, n0 = nt << 8;
  const u16* B = (m0 < split) ? Benc : Bimg;
  const float* bias = (m0 < split) ? biasEnc : biasImg;

  __shared__ u16 lds[4][2][8192];  // [buf][A=0/B=1][16 units x 1 KB] = 128 KiB

  const int tid = threadIdx.x, w = tid >> 6, lane = tid & 63;
  const int wm = w >> 2, wn = w & 3;       // 2M x 4N waves
  const int q = lane & 15, hi = lane >> 4;
  const size_t ldb = (size_t)K * 2;        // row stride bytes

  f32x4 acc[8][4];
#pragma unroll
  for (int i = 0; i < 8; ++i)
#pragma unroll
    for (int j = 0; j < 4; ++j)
#pragma unroll
      for (int r = 0; r < 4; ++r) acc[i][j][r] = 0.f;

  // stage one BK=32 tile (A 256x32 + B 256x32) into buf b: 4 glls/thread
  auto STAGE = [&](int b, int kt) {
    const char* sA = (const char*)A + (size_t)m0 * ldb + (size_t)kt * 64;
    const char* sB = (const char*)B + (size_t)n0 * ldb + (size_t)kt * 64;
    char* dA = (char*)&lds[b][0][0];
    char* dB = (char*)&lds[b][1][0];
#pragma unroll
    for (int g = 0; g < 2; ++g) {
      const int u = g * 8 + w;
      const size_t so = (size_t)(u * 16 + q) * ldb + hi * 16;
      GLL16(sA + so, dA + u * 1024 + lane * 16);
      GLL16(sB + so, dB + u * 1024 + lane * 16);
    }
  };
  auto LDA = [&](int b, int i) -> bf16x8 {
    return *(const bf16x8*)((const char*)&lds[b][0][0] + (wm * 8 + i) * 1024 + lane * 16);
  };
  auto LDB = [&](int b, int j) -> bf16x8 {
    return *(const bf16x8*)((const char*)&lds[b][1][0] + (wn * 4 + j) * 1024 + lane * 16);
  };

  const int NT = K >> 5;  // 96 tiles
  STAGE(0, 0); STAGE(1, 1); STAGE(2, 2);
  VMC8();   // 12 outstanding -> tile 0's 4 landed (tiles 1,2 in flight)
  BAR();
  for (int t = 0; t < NT; ++t) {
    const int b = t & 3;
    // fine phase: ds_read issue -> stage issue -> MFMA consume
    bf16x8 bfr[4];
#pragma unroll
    for (int j = 0; j < 4; ++j) bfr[j] = LDB(b, j);
    bf16x8 af[8];
#pragma unroll
    for (int i = 0; i < 8; ++i) af[i] = LDA(b, i);
    if (t + 3 < NT) STAGE((t + 3) & 3, t + 3);   // buf (t-1)%4: dead 2 barriers
    __builtin_amdgcn_s_setprio(1);
#pragma unroll
    for (int i = 0; i < 8; ++i)
#pragma unroll
      for (int j = 0; j < 4; ++j)
        acc[i][j] = __builtin_amdgcn_mfma_f32_16x16x32_bf16(af[i], bfr[j], acc[i][j], 0, 0, 0);
    __builtin_amdgcn_s_setprio(0);
    // counted drain: ensure tile t+1 landed before crossing the barrier
    const int rem = NT - 1 - t;     // future tiles staged = min(rem, 3)
    if (rem >= 3)      VMC8();      // 3 in flight -> wait oldest (t+1)
    else if (rem == 2) VMC4();
    else if (rem == 1) VMC0();
    BAR();                          // buf b reusable for staging at t+1
  }

  // epilogue: row = m0 + wm*128 + i*16 + hi*4 + r,  col = n0 + wn*64 + j*16 + q
#pragma unroll
  for (int i = 0; i < 8; ++i) {
    int rbase = m0 + wm * 128 + i * 16 + (hi << 2);
#pragma unroll
    for (int j = 0; j < 4; ++j) {
      int col = n0 + wn * 64 + j * 16 + q;
      float bv = bias ? bias[col] : 0.f;
#pragma unroll
      for (int r = 0; r < 4; ++r) {
        int row = rbase + r;
        float v = acc[i][j][r] + bv;
        if (row < split) store_out(&Cenc[(size_t)row * N + col], v);
        else             store_out(&Cimg[(size_t)(row - split) * N + col], v);
      }
    }
  }
}

// ---------------- per-head RMSnorm(q,k) + RoPE(q,k), emit V^T -----------------
// Q pre-scaled by log2(e)/sqrt(128) so attn scores land in log2 units.
__global__ __launch_bounds__(256) void norm_rope(
    u16* __restrict__ qkv, u16* __restrict__ vt,
    const float* __restrict__ cosT, const float* __restrict__ sinT,
    const float* __restrict__ nqw_img, const float* __restrict__ nkw_img,
    const float* __restrict__ nqw_enc, const float* __restrict__ nkw_enc) {
  const int h = blockIdx.y;
  const int s0 = blockIdx.x * 64;
  const int tid = threadIdx.x, w = tid >> 6, lane = tid & 63;
  const bool enc = (s0 < 512);
  const float* nqw = enc ? nqw_enc : nqw_img;
  const float* nkw = enc ? nkw_enc : nkw_img;
  const float SCL = 0.12751743f;  // log2(e)/sqrt(128)
  const float wq0 = nqw[2 * lane], wq1 = nqw[2 * lane + 1];
  const float wk0 = nkw[2 * lane], wk1 = nkw[2 * lane + 1];
  u16x8 va0, va1, vb0, vb1;
#pragma unroll
  for (int r = 0; r < 16; ++r) {
    const int s = s0 + w * 16 + r;
    const size_t rowb = (size_t)s * 9216 + h * 128 + 2 * lane;
    float2 cv = *(const float2*)&cosT[(size_t)s * 128 + 2 * lane];
    float2 sv = *(const float2*)&sinT[(size_t)s * 128 + 2 * lane];
    {  // Q
      u16x2 qu = *(u16x2*)&qkv[rowb];
      float x0 = bf2f(qu.x), x1 = bf2f(qu.y);
      float ss = x0 * x0 + x1 * x1;
#pragma unroll
      for (int d = 1; d < 64; d <<= 1) ss += __shfl_xor(ss, d);
      float rms = rsqrtf(ss * (1.0f / 128.0f) + 1e-5f);
      x0 *= rms * wq0; x1 *= rms * wq1;
      float o0 = (x0 * cv.x - x1 * sv.x) * SCL;
      float o1 = (x1 * cv.y + x0 * sv.y) * SCL;
      u16x2 ou; ou.x = f2bf(o0); ou.y = f2bf(o1);
      *(u16x2*)&qkv[rowb] = ou;
    }
    {  // K
      u16x2 ku = *(u16x2*)&qkv[rowb + 3072];
      float x0 = bf2f(ku.x), x1 = bf2f(ku.y);
      float ss = x0 * x0 + x1 * x1;
#pragma unroll
      for (int d = 1; d < 64; d <<= 1) ss += __shfl_xor(ss, d);
      float rms = rsqrtf(ss * (1.0f / 128.0f) + 1e-5f);
      x0 *= rms * wk0; x1 *= rms * wk1;
      float o0 = x0 * cv.x - x1 * sv.x;
      float o1 = x1 * cv.y + x0 * sv.y;
      u16x2 ou; ou.x = f2bf(o0); ou.y = f2bf(o1);
      *(u16x2*)&qkv[rowb + 3072] = ou;
    }
    {  // V -> registers for transposed store
      u16x2 vu = *(u16x2*)&qkv[rowb + 6144];
      if (r < 8) { va0[r] = vu.x; vb0[r] = vu.y; }
      else       { va1[r - 8] = vu.x; vb1[r - 8] = vu.y; }
    }
  }
  const size_t vbase = (size_t)h * 128 * 3584 + (size_t)(2 * lane) * 3584 + s0 + w * 16;
  *(u16x8*)&vt[vbase]            = va0;
  *(u16x8*)&vt[vbase + 8]        = va1;
  *(u16x8*)&vt[vbase + 3584]     = vb0;
  *(u16x8*)&vt[vbase + 3584 + 8] = vb1;
}

// ---------------- flash attention (32x32 MFMA, in-reg P, KVBLK=32) ----------
// (unchanged from R10/R12 — ~200 us class; launch_bounds (256,2), no spill)
__global__ __launch_bounds__(256, 2) void attn_kernel(
    const u16* __restrict__ qkv, const u16* __restrict__ vt,
    u16* __restrict__ aout) {
  const int bid = blockIdx.x;
  const int qt = bid / 24;
  const int rr = bid % 24;
  const int h = (rr % 8) * 3 + (rr / 8);   // bijective; clusters heads per XCD
  const int tid = threadIdx.x, w = tid >> 6, lane = tid & 63;
  const int q32 = lane & 31, hi5 = lane >> 5;
  const int qbase = qt * 128 + w * 32;
  __shared__ u16 Klds[2][4096];   // 8 KB/buf: byte = ds*1024 + lane*16
  __shared__ u16 Vlds[2][4096];   // 8 KB/buf: byte = (dt*2+ks)*1024 + lane*16

  bf16x8 aq[8];
  {
    const u16* qp = qkv + (size_t)(qbase + q32) * 9216 + h * 128 + hi5 * 8;
#pragma unroll
    for (int ds = 0; ds < 8; ++ds) aq[ds] = *(const bf16x8*)(qp + ds * 16);
  }
  float m_i = -1e30f, l_i = 0.f;
  f32x16 o[4];
#pragma unroll
  for (int dt = 0; dt < 4; ++dt)
#pragma unroll
    for (int r = 0; r < 16; ++r) o[dt][r] = 0.f;
  const size_t vhead = (size_t)h * 128 * 3584;

  auto STAGE_K = [&](int kt0, int b) {
    const char* src = (const char*)(qkv + (size_t)(kt0 + q32) * 9216 + 3072 + h * 128) + hi5 * 16;
    char* dst = (char*)Klds[b] + w * 2048 + lane * 16;
#pragma unroll
    for (int j = 0; j < 2; ++j)
      GLL16(src + (w * 2 + j) * 32, dst + j * 1024);
  };
  auto STAGE_V = [&](int kt0, int b) {
    char* dst = (char*)Vlds[b] + w * 2048 + lane * 16;
#pragma unroll
    for (int j = 0; j < 2; ++j) {
      const int u = w * 2 + j, dt = u >> 1, ks = u & 1;
      GLL16((const char*)(vt + vhead + (size_t)(dt * 32 + q32) * 3584 + kt0) + ks * 32 + hi5 * 16,
            dst + j * 1024);
    }
  };

  auto PACK = [&](const float* p, bf16x8* out2) {
    unsigned w0[4], w1[4];
#pragma unroll
    for (int g = 0; g < 4; ++g) {
      asm("v_cvt_pk_bf16_f32 %0, %1, %2" : "=v"(w0[g]) : "v"(p[4 * g + 0]), "v"(p[4 * g + 1]));
      asm("v_cvt_pk_bf16_f32 %0, %1, %2" : "=v"(w1[g]) : "v"(p[4 * g + 2]), "v"(p[4 * g + 3]));
    }
    asm("v_permlane32_swap_b32 %0, %1" : "+v"(w0[0]), "+v"(w0[1]));
    asm("v_permlane32_swap_b32 %0, %1" : "+v"(w1[0]), "+v"(w1[1]));
    asm("v_permlane32_swap_b32 %0, %1" : "+v"(w0[2]), "+v"(w0[3]));
    asm("v_permlane32_swap_b32 %0, %1" : "+v"(w1[2]), "+v"(w1[3]));
    u32x4 lo = {w0[0], w1[0], w0[1], w1[1]};   // klocal 0-15
    u32x4 hi_ = {w0[2], w1[2], w0[3], w1[3]};  // klocal 16-31
    out2[0] = __builtin_bit_cast(bf16x8, lo);
    out2[1] = __builtin_bit_cast(bf16x8, hi_);
  };

  const int NT = 112;  // 3584 / 32
  STAGE_K(0, 0);   STAGE_V(0, 0);
  STAGE_K(32, 1);  STAGE_V(32, 1);
  for (int t = 0; t < NT; ++t) {
    const int b = t & 1;
    if (t + 1 < NT) VMC4(); else VMC0();
    BAR();

    f32x16 s0;
#pragma unroll
    for (int r = 0; r < 16; ++r) s0[r] = 0.f;
    __builtin_amdgcn_s_setprio(1);
#pragma unroll
    for (int ds = 0; ds < 8; ++ds) {
      bf16x8 k0 = *(const bf16x8*)((const char*)Klds[b] + ds * 1024 + lane * 16);
      s0 = __builtin_amdgcn_mfma_f32_32x32x16_bf16(k0, aq[ds], s0, 0, 0, 0);
    }
    __builtin_amdgcn_s_setprio(0);

    float mx = s0[0];
#pragma unroll
    for (int r = 1; r < 16; ++r) mx = fmaxf(mx, s0[r]);
    mx = fmaxf(mx, __shfl_xor(mx, 32));
    if (!__all(mx - m_i <= 8.f)) {
      float mnew = fmaxf(m_i, mx);
      float alpha = __builtin_amdgcn_exp2f(m_i - mnew);
      m_i = mnew;
      l_i *= alpha;
#pragma unroll
      for (int r = 0; r < 16; ++r) {
        int qr = (r & 3) + 8 * (r >> 2) + 4 * hi5;
        float ar = __shfl(alpha, qr);
#pragma unroll
        for (int dt = 0; dt < 4; ++dt) o[dt][r] *= ar;
      }
    }
    float p0[16];
    float psum = 0.f;
#pragma unroll
    for (int r = 0; r < 16; ++r) { p0[r] = __builtin_amdgcn_exp2f(s0[r] - m_i); psum += p0[r]; }
    psum += __shfl_xor(psum, 32);
    l_i += psum;

    bf16x8 pa[2];
    PACK(p0, pa);

    __builtin_amdgcn_s_setprio(1);
#pragma unroll
    for (int dt = 0; dt < 4; ++dt) {
#pragma unroll
      for (int ks = 0; ks < 2; ++ks) {
        bf16x8 bv = *(const bf16x8*)((const char*)Vlds[b] + (dt * 2 + ks) * 1024 + lane * 16);
        o[dt] = __builtin_amdgcn_mfma_f32_32x32x16_bf16(pa[ks], bv, o[dt], 0, 0, 0);
      }
    }
    __builtin_amdgcn_s_setprio(0);
    BAR();
    if (t + 2 < NT) { STAGE_K((t + 2) * 32, b); STAGE_V((t + 2) * 32, b); }
  }

#pragma unroll
  for (int r = 0; r < 16; ++r) {
    const int qr = (r & 3) + 8 * (r >> 2) + 4 * hi5;
    const float lr = __shfl(l_i, qr);
    const float inv = 1.0f / lr;
    const size_t srow = (size_t)(qbase + qr) * 3072 + h * 128 + q32;
#pragma unroll
    for (int dt = 0; dt < 4; ++dt)
      aout[srow + dt * 32] = f2bf(o[dt][r] * inv);
  }
}

extern "C" void kernel_launch(void* const* d_in, const int* in_sizes, int n_in,
                              void* d_out, int out_size, void* d_ws, size_t ws_size,
                              hipStream_t stream) {
  (void)in_sizes; (void)n_in; (void)out_size; (void)ws_size;
  const float* hs    = (const float*)d_in[0];
  const float* ehs   = (const float*)d_in[1];
  const float* cosT  = (const float*)d_in[2];
  const float* sinT  = (const float*)d_in[3];
  const float* Wqkv  = (const float*)d_in[4];
  const float* Wadd  = (const float*)d_in[5];
  const float* bAdd  = (const float*)d_in[6];
  const float* nqw   = (const float*)d_in[7];
  const float* nkw   = (const float*)d_in[8];
  const float* naqw  = (const float*)d_in[9];
  const float* nakw  = (const float*)d_in[10];
  const float* Wout  = (const float*)d_in[11];
  const float* bout  = (const float*)d_in[12];
  const float* Waddo = (const float*)d_in[13];
  const float* baddo = (const float*)d_in[14];

  char* ws = (char*)d_ws;
  u16* Ain = (u16*)(ws);                       // [3584][3072]
  u16* WqI = (u16*)(ws + 22020096);            // [9216][3072]
  u16* WqE = WqI + (size_t)9216 * 3072;
  u16* WoI = (u16*)(ws + 135266304);           // [3072][3072]
  u16* WoE = WoI + (size_t)3072 * 3072;
  u16* qkv = (u16*)(ws + 173015040);           // [3584][9216]
  u16* vt   = Ain;  // alias: A_in dead after QKV GEMM
  u16* aout = WqI;  // alias: W_qkv dead after QKV GEMM

  cvt_kernel<<<1024, 256, 0, stream>>>(ehs,   Ain,                      512 * 3072 / 4);
  cvt_kernel<<<1024, 256, 0, stream>>>(hs,    Ain + (size_t)512 * 3072, 3072 * 3072 / 4);
  cvt_kernel<<<2048, 256, 0, stream>>>(Wqkv,  WqI, 9216 * 3072 / 4);
  cvt_kernel<<<2048, 256, 0, stream>>>(Wadd,  WqE, 9216 * 3072 / 4);
  cvt_kernel<<<1024, 256, 0, stream>>>(Wout,  WoI, 3072 * 3072 / 4);
  cvt_kernel<<<1024, 256, 0, stream>>>(Waddo, WoE, 3072 * 3072 / 4);

  // QKV: [3584][9216] = A_in x W^T (+ bias on enc rows), bf16 out (internal)
  gemm256<u16><<<dim3(504), 512, 0, stream>>>(Ain, WqI, WqE, nullptr, bAdd,
                                              qkv + (size_t)512 * 9216, qkv, 9216, 3072, 512);
  norm_rope<<<dim3(56, 24), 256, 0, stream>>>(qkv, vt, cosT, sinT, nqw, nkw, naqw, nakw);
  attn_kernel<<<dim3(672), 256, 0, stream>>>(qkv, vt, aout);
  // out proj: FLOAT32 output — img rows -> d_out[0:3072*3072], enc rows after
  float* outp = (float*)d_out;
  gemm256<float><<<dim3(168), 512, 0, stream>>>(aout, WoI, WoE, bout, baddo,
                                                outp, outp + (size_t)3072 * 3072, 3072, 3072, 512);
}

// Round 14
// 636.212 us; speedup vs baseline: 1.0460x; 1.0460x over previous
//
#include <hip/hip_runtime.h>

// Flux2 double-stream attention block, bf16 MFMA pipeline, f32 final output.
// Stages: fused cvt(f32->bf16) -> QKV GEMM (8-phase 256^2, 2-D XCD)
//         -> RMSnorm+RoPE(+V^T) -> flash attn (3-buf, 1 barrier/tile) -> out GEMM.
// ws layout (bytes):
//   [0,           22020096)  A_in bf16 [3584][3072]   } later aliased by V^T [24][128][3584]
//   [22020096,   135266304)  Wq bf16: img [9216][3072] then enc } later aliased by attn_out
//   [135266304,  173015040)  Wo bf16: img [3072][3072] then enc
//   [173015040,  239075328)  qkv bf16 [3584][9216]
// peak ws = 239,075,328 B.

typedef unsigned short u16;
typedef __attribute__((ext_vector_type(2))) unsigned short u16x2;
typedef __attribute__((ext_vector_type(4))) unsigned short u16x4;
typedef __attribute__((ext_vector_type(8))) unsigned short u16x8;
typedef __attribute__((ext_vector_type(8))) short bf16x8;
typedef __attribute__((ext_vector_type(4))) float f32x4;
typedef __attribute__((ext_vector_type(16))) float f32x16;
typedef __attribute__((ext_vector_type(4))) unsigned u32x4;

#define DEV __device__ __forceinline__

DEV u16 f2bf(float f) {
  unsigned u = __builtin_bit_cast(unsigned, f);
  u = (u + 0x7FFFu + ((u >> 16) & 1u)) >> 16;   // RNE
  return (u16)u;
}
DEV float bf2f(u16 s) { return __builtin_bit_cast(float, (unsigned)s << 16); }

DEV void store_out(u16* p, float v)  { *p = f2bf(v); }
DEV void store_out(float* p, float v) { *p = v; }

#define AS1(p) (const __attribute__((address_space(1))) void*)(p)
#define AS3(p) (__attribute__((address_space(3))) void*)(p)
#define GLL16(g, l) __builtin_amdgcn_global_load_lds(AS1(g), AS3(l), 16, 0, 0)

// raw barrier (NOT __syncthreads: that emits s_waitcnt vmcnt(0) and drains the
// counted-vmcnt pipeline). Compiler-only memory fences pin op order around it.
#define BAR() do { asm volatile("" ::: "memory"); __builtin_amdgcn_s_barrier(); \
                   asm volatile("" ::: "memory"); } while (0)
#define VMC8() asm volatile("s_waitcnt vmcnt(8)" ::: "memory")
#define VMC4() asm volatile("s_waitcnt vmcnt(4)" ::: "memory")
#define VMC0() asm volatile("s_waitcnt vmcnt(0)" ::: "memory")

// ---------------- fused fp32 -> bf16 convert (6 segments, 1 dispatch) -------
// Segment boundaries in float4 units (compile-time constants).
__global__ __launch_bounds__(256) void cvt_all(
    const float* __restrict__ s0, const float* __restrict__ s1,
    const float* __restrict__ s2, const float* __restrict__ s3,
    const float* __restrict__ s4, const float* __restrict__ s5,
    u16* __restrict__ ws16) {
  // f4-unit boundaries: ehs 393216 | hs 2359296 | Wqkv 7077888 | Wadd 7077888
  //                     | Wout 2359296 | Waddo 2359296
  constexpr int B1 = 393216, B2 = 2752512, B3 = 9830400,
                B4 = 16908288, B5 = 19267584, B6 = 21626880;
  int i = blockIdx.x * blockDim.x + threadIdx.x;
  int stride = gridDim.x * blockDim.x;
  for (; i < B6; i += stride) {
    const float* src; size_t off; u16* dst;
    if (i < B1)      { src = s0; off = i;      dst = ws16; }
    else if (i < B2) { src = s1; off = i - B1; dst = ws16 + 1572864; }
    else if (i < B3) { src = s2; off = i - B2; dst = ws16 + 11010048; }
    else if (i < B4) { src = s3; off = i - B3; dst = ws16 + 39321600; }
    else if (i < B5) { src = s4; off = i - B4; dst = ws16 + 67633152; }
    else             { src = s5; off = i - B5; dst = ws16 + 77070336; }
    float4 v = reinterpret_cast<const float4*>(src)[off];
    u16x4 o;
    o.x = f2bf(v.x); o.y = f2bf(v.y); o.z = f2bf(v.z); o.w = f2bf(v.w);
    reinterpret_cast<u16x4*>(dst)[off] = o;
  }
}

// ---------------- GEMM (8-phase 256x256): C = A[M][K] * B[N][K]^T (+bias) ----
// R12-verified: BK=64, 128 KiB dbuf, 4 fine phases/half, vmcnt(8) counted,
// setprio, 2-D XCD chunk decode (FETCH 408->189 MB).
template <typename OT>
__global__ __launch_bounds__(512, 2) void gemm256(
    const u16* __restrict__ A,
    const u16* __restrict__ Bimg, const u16* __restrict__ Benc,
    const float* __restrict__ biasImg, const float* __restrict__ biasEnc,
    OT* __restrict__ Cimg, OT* __restrict__ Cenc,
    int N, int K, int split) {
  const int bid = blockIdx.x;
  const int ntn = N >> 8;
  const int CN = ntn >> 2;                 // nt per XCD band
  const int x = bid & 7, i5 = bid >> 3;    // XCD id, in-chunk index
  const int mt = (x >> 2) * 7 + i5 / CN;
  const int nt = (x & 3) * CN + i5 % CN;
  const int m0 = mt << 8, n0 = nt << 8;
  const u16* B = (m0 < split) ? Benc : Bimg;
  const float* bias = (m0 < split) ? biasEnc : biasImg;

  __shared__ u16 lds[2][2][16384];  // [buf][A=0/B=1][256 rows x 64 bf16] x2 = 128 KiB

  const int tid = threadIdx.x, w = tid >> 6, lane = tid & 63;
  const int wm = w >> 2, wn = w & 3;
  const int q = lane & 15, hi = lane >> 4;
  const size_t ldb = (size_t)K * 2;

  f32x4 acc[8][4];
#pragma unroll
  for (int i = 0; i < 8; ++i)
#pragma unroll
    for (int j = 0; j < 4; ++j)
#pragma unroll
      for (int r = 0; r < 4; ++r) acc[i][j][r] = 0.f;

  auto STAGE = [&](int d, int kt) {
    const char* sA = (const char*)A + (size_t)m0 * ldb + kt * 128;
    const char* sB = (const char*)B + (size_t)n0 * ldb + kt * 128;
    char* dA = (char*)&lds[d][0][0];
    char* dB = (char*)&lds[d][1][0];
#pragma unroll
    for (int j = 0; j < 4; ++j) {
      int base = j * 8192 + w * 1024;
      int off = base + lane * 16;
      int row = off >> 7;
      int src = (off & 127) ^ ((row & 7) << 4);
      GLL16(sA + (size_t)row * ldb + src, dA + base);
      GLL16(sB + (size_t)row * ldb + src, dB + base);
    }
  };
  auto LDA = [&](int d, int i, int ks) -> bf16x8 {
    int row = wm * 128 + i * 16 + q;
    int cb = ks * 64 + hi * 16;
    return *(const bf16x8*)((const char*)&lds[d][0][0] + row * 128 + (cb ^ ((row & 7) << 4)));
  };
  auto LDB = [&](int d, int j, int ks) -> bf16x8 {
    int row = wn * 64 + j * 16 + q;
    int cb = ks * 64 + hi * 16;
    return *(const bf16x8*)((const char*)&lds[d][1][0] + row * 128 + (cb ^ ((row & 7) << 4)));
  };

  auto HALF = [&](int d) {
    bf16x8 bfr[4][2];
#pragma unroll
    for (int ph = 0; ph < 4; ++ph) {
      if (ph == 0) {
#pragma unroll
        for (int j = 0; j < 4; ++j)
#pragma unroll
          for (int ks = 0; ks < 2; ++ks) bfr[j][ks] = LDB(d, j, ks);
      }
      bf16x8 af[2][2];
#pragma unroll
      for (int m = 0; m < 2; ++m)
#pragma unroll
        for (int ks = 0; ks < 2; ++ks) af[m][ks] = LDA(d, 2 * ph + m, ks);
      __builtin_amdgcn_s_setprio(1);
#pragma unroll
      for (int m = 0; m < 2; ++m)
#pragma unroll
        for (int j = 0; j < 4; ++j)
#pragma unroll
          for (int ks = 0; ks < 2; ++ks)
            acc[2 * ph + m][j] = __builtin_amdgcn_mfma_f32_16x16x32_bf16(
                af[m][ks], bfr[j][ks], acc[2 * ph + m][j], 0, 0, 0);
      __builtin_amdgcn_s_setprio(0);
      if (ph < 3) BAR();
    }
  };

  const int NT2 = K >> 7;
  STAGE(0, 0);
  STAGE(1, 1);
  VMC8();
  BAR();
  for (int t = 0; t < NT2; ++t) {
    HALF(0);
    BAR();
    if (t + 1 < NT2) { STAGE(0, 2 * t + 2); VMC8(); }
    else             VMC0();
    BAR();
    HALF(1);
    BAR();
    if (t + 1 < NT2) { STAGE(1, 2 * t + 3); VMC8(); }
    else             VMC0();
    BAR();
  }

#pragma unroll
  for (int i = 0; i < 8; ++i) {
    int rbase = m0 + wm * 128 + i * 16 + (hi << 2);
#pragma unroll
    for (int j = 0; j < 4; ++j) {
      int col = n0 + wn * 64 + j * 16 + q;
      float bv = bias ? bias[col] : 0.f;
#pragma unroll
      for (int r = 0; r < 4; ++r) {
        int row = rbase + r;
        float v = acc[i][j][r] + bv;
        if (row < split) store_out(&Cenc[(size_t)row * N + col], v);
        else             store_out(&Cimg[(size_t)(row - split) * N + col], v);
      }
    }
  }
}

// ---------------- per-head RMSnorm(q,k) + RoPE(q,k), emit V^T -----------------
// Q pre-scaled by log2(e)/sqrt(128) so attn scores land in log2 units.
__global__ __launch_bounds__(256) void norm_rope(
    u16* __restrict__ qkv, u16* __restrict__ vt,
    const float* __restrict__ cosT, const float* __restrict__ sinT,
    const float* __restrict__ nqw_img, const float* __restrict__ nkw_img,
    const float* __restrict__ nqw_enc, const float* __restrict__ nkw_enc) {
  const int h = blockIdx.y;
  const int s0 = blockIdx.x * 64;
  const int tid = threadIdx.x, w = tid >> 6, lane = tid & 63;
  const bool enc = (s0 < 512);
  const float* nqw = enc ? nqw_enc : nqw_img;
  const float* nkw = enc ? nkw_enc : nkw_img;
  const float SCL = 0.12751743f;  // log2(e)/sqrt(128)
  const float wq0 = nqw[2 * lane], wq1 = nqw[2 * lane + 1];
  const float wk0 = nkw[2 * lane], wk1 = nkw[2 * lane + 1];
  u16x8 va0, va1, vb0, vb1;
#pragma unroll
  for (int r = 0; r < 16; ++r) {
    const int s = s0 + w * 16 + r;
    const size_t rowb = (size_t)s * 9216 + h * 128 + 2 * lane;
    float2 cv = *(const float2*)&cosT[(size_t)s * 128 + 2 * lane];
    float2 sv = *(const float2*)&sinT[(size_t)s * 128 + 2 * lane];
    {  // Q
      u16x2 qu = *(u16x2*)&qkv[rowb];
      float x0 = bf2f(qu.x), x1 = bf2f(qu.y);
      float ss = x0 * x0 + x1 * x1;
#pragma unroll
      for (int d = 1; d < 64; d <<= 1) ss += __shfl_xor(ss, d);
      float rms = rsqrtf(ss * (1.0f / 128.0f) + 1e-5f);
      x0 *= rms * wq0; x1 *= rms * wq1;
      float o0 = (x0 * cv.x - x1 * sv.x) * SCL;
      float o1 = (x1 * cv.y + x0 * sv.y) * SCL;
      u16x2 ou; ou.x = f2bf(o0); ou.y = f2bf(o1);
      *(u16x2*)&qkv[rowb] = ou;
    }
    {  // K
      u16x2 ku = *(u16x2*)&qkv[rowb + 3072];
      float x0 = bf2f(ku.x), x1 = bf2f(ku.y);
      float ss = x0 * x0 + x1 * x1;
#pragma unroll
      for (int d = 1; d < 64; d <<= 1) ss += __shfl_xor(ss, d);
      float rms = rsqrtf(ss * (1.0f / 128.0f) + 1e-5f);
      x0 *= rms * wk0; x1 *= rms * wk1;
      float o0 = x0 * cv.x - x1 * sv.x;
      float o1 = x1 * cv.y + x0 * sv.y;
      u16x2 ou; ou.x = f2bf(o0); ou.y = f2bf(o1);
      *(u16x2*)&qkv[rowb + 3072] = ou;
    }
    {  // V -> registers for transposed store
      u16x2 vu = *(u16x2*)&qkv[rowb + 6144];
      if (r < 8) { va0[r] = vu.x; vb0[r] = vu.y; }
      else       { va1[r - 8] = vu.x; vb1[r - 8] = vu.y; }
    }
  }
  const size_t vbase = (size_t)h * 128 * 3584 + (size_t)(2 * lane) * 3584 + s0 + w * 16;
  *(u16x8*)&vt[vbase]            = va0;
  *(u16x8*)&vt[vbase + 8]        = va1;
  *(u16x8*)&vt[vbase + 3584]     = vb0;
  *(u16x8*)&vt[vbase + 3584 + 8] = vb1;
}

// ---------------- flash attention (32x32 MFMA, in-reg P, KVBLK=32) ----------
// NEW in R14: 3 rotating K/V buffers (48 KB) with ONE barrier per tile.
// Race-freedom: stage at end of tile t targets buf (t+2)%3 = (t-1)%3, which
// every wave stopped reading before the top-of-t barrier; bufs t%3 (reads) and
// (t+1)%3 (in flight) are disjoint from the stage target. vmcnt(8) at top of
// t waits exactly tile t (t+1's 8 glls stay in flight, issued a full tile
// earlier -> ~2-tile latency cover). Barriers/tile: 2 -> 1.
__global__ __launch_bounds__(256, 2) void attn_kernel(
    const u16* __restrict__ qkv, const u16* __restrict__ vt,
    u16* __restrict__ aout) {
  const int bid = blockIdx.x;
  const int qt = bid / 24;
  const int rr = bid % 24;
  const int h = (rr % 8) * 3 + (rr / 8);   // bijective; clusters heads per XCD
  const int tid = threadIdx.x, w = tid >> 6, lane = tid & 63;
  const int q32 = lane & 31, hi5 = lane >> 5;
  const int qbase = qt * 128 + w * 32;
  __shared__ u16 Klds[3][4096];   // 8 KB/buf: byte = ds*1024 + lane*16
  __shared__ u16 Vlds[3][4096];   // 8 KB/buf: byte = (dt*2+ks)*1024 + lane*16

  bf16x8 aq[8];
  {
    const u16* qp = qkv + (size_t)(qbase + q32) * 9216 + h * 128 + hi5 * 8;
#pragma unroll
    for (int ds = 0; ds < 8; ++ds) aq[ds] = *(const bf16x8*)(qp + ds * 16);
  }
  float m_i = -1e30f, l_i = 0.f;
  f32x16 o[4];
#pragma unroll
  for (int dt = 0; dt < 4; ++dt)
#pragma unroll
    for (int r = 0; r < 16; ++r) o[dt][r] = 0.f;
  const size_t vhead = (size_t)h * 128 * 3584;

  auto STAGE_K = [&](int kt0, int b) {
    const char* src = (const char*)(qkv + (size_t)(kt0 + q32) * 9216 + 3072 + h * 128) + hi5 * 16;
    char* dst = (char*)Klds[b] + w * 2048 + lane * 16;
#pragma unroll
    for (int j = 0; j < 2; ++j)
      GLL16(src + (w * 2 + j) * 32, dst + j * 1024);
  };
  auto STAGE_V = [&](int kt0, int b) {
    char* dst = (char*)Vlds[b] + w * 2048 + lane * 16;
#pragma unroll
    for (int j = 0; j < 2; ++j) {
      const int u = w * 2 + j, dt = u >> 1, ks = u & 1;
      GLL16((const char*)(vt + vhead + (size_t)(dt * 32 + q32) * 3584 + kt0) + ks * 32 + hi5 * 16,
            dst + j * 1024);
    }
  };

  auto PACK = [&](const float* p, bf16x8* out2) {
    unsigned w0[4], w1[4];
#pragma unroll
    for (int g = 0; g < 4; ++g) {
      asm("v_cvt_pk_bf16_f32 %0, %1, %2" : "=v"(w0[g]) : "v"(p[4 * g + 0]), "v"(p[4 * g + 1]));
      asm("v_cvt_pk_bf16_f32 %0, %1, %2" : "=v"(w1[g]) : "v"(p[4 * g + 2]), "v"(p[4 * g + 3]));
    }
    asm("v_permlane32_swap_b32 %0, %1" : "+v"(w0[0]), "+v"(w0[1]));
    asm("v_permlane32_swap_b32 %0, %1" : "+v"(w1[0]), "+v"(w1[1]));
    asm("v_permlane32_swap_b32 %0, %1" : "+v"(w0[2]), "+v"(w0[3]));
    asm("v_permlane32_swap_b32 %0, %1" : "+v"(w1[2]), "+v"(w1[3]));
    u32x4 lo = {w0[0], w1[0], w0[1], w1[1]};   // klocal 0-15
    u32x4 hi_ = {w0[2], w1[2], w0[3], w1[3]};  // klocal 16-31
    out2[0] = __builtin_bit_cast(bf16x8, lo);
    out2[1] = __builtin_bit_cast(bf16x8, hi_);
  };

  const int NT = 112;  // 3584 / 32
  STAGE_K(0, 0);   STAGE_V(0, 0);
  STAGE_K(32, 1);  STAGE_V(32, 1);
  int cur = 0;
  for (int t = 0; t < NT; ++t) {
    if (t + 1 < NT) VMC8(); else VMC0();   // tile t landed (t+1 in flight)
    BAR();                                 // single barrier per tile

    f32x16 s0;
#pragma unroll
    for (int r = 0; r < 16; ++r) s0[r] = 0.f;
    __builtin_amdgcn_s_setprio(1);
#pragma unroll
    for (int ds = 0; ds < 8; ++ds) {
      bf16x8 k0 = *(const bf16x8*)((const char*)Klds[cur] + ds * 1024 + lane * 16);
      s0 = __builtin_amdgcn_mfma_f32_32x32x16_bf16(k0, aq[ds], s0, 0, 0, 0);
    }
    __builtin_amdgcn_s_setprio(0);

    float mx = s0[0];
#pragma unroll
    for (int r = 1; r < 16; ++r) mx = fmaxf(mx, s0[r]);
    mx = fmaxf(mx, __shfl_xor(mx, 32));
    if (!__all(mx - m_i <= 8.f)) {
      float mnew = fmaxf(m_i, mx);
      float alpha = __builtin_amdgcn_exp2f(m_i - mnew);
      m_i = mnew;
      l_i *= alpha;
#pragma unroll
      for (int r = 0; r < 16; ++r) {
        int qr = (r & 3) + 8 * (r >> 2) + 4 * hi5;
        float ar = __shfl(alpha, qr);
#pragma unroll
        for (int dt = 0; dt < 4; ++dt) o[dt][r] *= ar;
      }
    }
    float p0[16];
    float psum = 0.f;
#pragma unroll
    for (int r = 0; r < 16; ++r) { p0[r] = __builtin_amdgcn_exp2f(s0[r] - m_i); psum += p0[r]; }
    psum += __shfl_xor(psum, 32);
    l_i += psum;

    bf16x8 pa[2];
    PACK(p0, pa);

    __builtin_amdgcn_s_setprio(1);
#pragma unroll
    for (int dt = 0; dt < 4; ++dt) {
#pragma unroll
      for (int ks = 0; ks < 2; ++ks) {
        bf16x8 bv = *(const bf16x8*)((const char*)Vlds[cur] + (dt * 2 + ks) * 1024 + lane * 16);
        o[dt] = __builtin_amdgcn_mfma_f32_32x32x16_bf16(pa[ks], bv, o[dt], 0, 0, 0);
      }
    }
    __builtin_amdgcn_s_setprio(0);

    if (t + 2 < NT) {                      // stage into buf (t+2)%3 == (t-1)%3
      const int stg = cur ? cur - 1 : 2;   // dead since top-of-t barrier
      STAGE_K((t + 2) * 32, stg);
      STAGE_V((t + 2) * 32, stg);
    }
    cur = (cur == 2) ? 0 : cur + 1;
  }

  // epilogue: O /= l (per-row l via shfl), bf16 scatter to attn_out[s][h*128+d]
#pragma unroll
  for (int r = 0; r < 16; ++r) {
    const int qr = (r & 3) + 8 * (r >> 2) + 4 * hi5;
    const float lr = __shfl(l_i, qr);
    const float inv = 1.0f / lr;
    const size_t srow = (size_t)(qbase + qr) * 3072 + h * 128 + q32;
#pragma unroll
    for (int dt = 0; dt < 4; ++dt)
      aout[srow + dt * 32] = f2bf(o[dt][r] * inv);
  }
}

extern "C" void kernel_launch(void* const* d_in, const int* in_sizes, int n_in,
                              void* d_out, int out_size, void* d_ws, size_t ws_size,
                              hipStream_t stream) {
  (void)in_sizes; (void)n_in; (void)out_size; (void)ws_size;
  const float* hs    = (const float*)d_in[0];
  const float* ehs   = (const float*)d_in[1];
  const float* cosT  = (const float*)d_in[2];
  const float* sinT  = (const float*)d_in[3];
  const float* Wqkv  = (const float*)d_in[4];
  const float* Wadd  = (const float*)d_in[5];
  const float* bAdd  = (const float*)d_in[6];
  const float* nqw   = (const float*)d_in[7];
  const float* nkw   = (const float*)d_in[8];
  const float* naqw  = (const float*)d_in[9];
  const float* nakw  = (const float*)d_in[10];
  const float* Wout  = (const float*)d_in[11];
  const float* bout  = (const float*)d_in[12];
  const float* Waddo = (const float*)d_in[13];
  const float* baddo = (const float*)d_in[14];

  char* ws = (char*)d_ws;
  u16* Ain = (u16*)(ws);                       // [3584][3072]
  u16* WqI = (u16*)(ws + 22020096);            // [9216][3072]
  u16* WqE = WqI + (size_t)9216 * 3072;
  u16* WoI = (u16*)(ws + 135266304);           // [3072][3072]
  u16* WoE = WoI + (size_t)3072 * 3072;
  u16* qkv = (u16*)(ws + 173015040);           // [3584][9216]
  u16* vt   = Ain;  // alias: A_in dead after QKV GEMM
  u16* aout = WqI;  // alias: W_qkv dead after QKV GEMM

  // single fused conversion dispatch (6 segments)
  cvt_all<<<4096, 256, 0, stream>>>(ehs, hs, Wqkv, Wadd, Wout, Waddo, (u16*)ws);

  // QKV: [3584][9216] = A_in x W^T (+ bias on enc rows), bf16 out (internal)
  gemm256<u16><<<dim3(504), 512, 0, stream>>>(Ain, WqI, WqE, nullptr, bAdd,
                                              qkv + (size_t)512 * 9216, qkv, 9216, 3072, 512);
  norm_rope<<<dim3(56, 24), 256, 0, stream>>>(qkv, vt, cosT, sinT, nqw, nkw, naqw, nakw);
  attn_kernel<<<dim3(672), 256, 0, stream>>>(qkv, vt, aout);
  // out proj: FLOAT32 output — img rows -> d_out[0:3072*3072], enc rows after
  float* outp = (float*)d_out;
  gemm256<float><<<dim3(168), 512, 0, stream>>>(aout, WoI, WoE, bout, baddo,
                                                outp, outp + (size_t)3072 * 3072, 3072, 3072, 512);
}

// Round 15
// 624.217 us; speedup vs baseline: 1.0661x; 1.0192x over previous
//
#include <hip/hip_runtime.h>

// Flux2 double-stream attention block, bf16 MFMA pipeline, f32 final output.
// Stages: fused cvt(f32->bf16) -> QKV GEMM (m201-faithful 8-phase) ->
//         RMSnorm+RoPE(+V^T) -> flash attn (3-buf, 1 bar/tile) -> out GEMM.
// ws layout (bytes):
//   [0,           22020096)  A_in bf16 [3584][3072]   } later aliased by V^T [24][128][3584]
//   [22020096,   135266304)  Wq bf16: img [9216][3072] then enc } later aliased by attn_out
//   [135266304,  173015040)  Wo bf16: img [3072][3072] then enc
//   [173015040,  239075328)  qkv bf16 [3584][9216]
// peak ws = 239,075,328 B.

typedef unsigned short u16;
typedef __attribute__((ext_vector_type(2))) unsigned short u16x2;
typedef __attribute__((ext_vector_type(4))) unsigned short u16x4;
typedef __attribute__((ext_vector_type(8))) unsigned short u16x8;
typedef __attribute__((ext_vector_type(8))) short bf16x8;
typedef __attribute__((ext_vector_type(4))) float f32x4;
typedef __attribute__((ext_vector_type(16))) float f32x16;
typedef __attribute__((ext_vector_type(4))) unsigned u32x4;

#define DEV __device__ __forceinline__

DEV u16 f2bf(float f) {
  unsigned u = __builtin_bit_cast(unsigned, f);
  u = (u + 0x7FFFu + ((u >> 16) & 1u)) >> 16;   // RNE
  return (u16)u;
}
DEV float bf2f(u16 s) { return __builtin_bit_cast(float, (unsigned)s << 16); }

DEV void store_out(u16* p, float v)  { *p = f2bf(v); }
DEV void store_out(float* p, float v) { *p = v; }

#define AS1(p) (const __attribute__((address_space(1))) void*)(p)
#define AS3(p) (__attribute__((address_space(3))) void*)(p)
#define GLL16(g, l) __builtin_amdgcn_global_load_lds(AS1(g), AS3(l), 16, 0, 0)

#define BAR() do { asm volatile("" ::: "memory"); __builtin_amdgcn_s_barrier(); \
                   asm volatile("" ::: "memory"); } while (0)
#define LGKM0() asm volatile("s_waitcnt lgkmcnt(0)" ::: "memory")
#define VMC8() asm volatile("s_waitcnt vmcnt(8)" ::: "memory")
#define VMC0() asm volatile("s_waitcnt vmcnt(0)" ::: "memory")

// ---------------- fused fp32 -> bf16 convert (6 segments, 1 dispatch) -------
__global__ __launch_bounds__(256) void cvt_all(
    const float* __restrict__ s0, const float* __restrict__ s1,
    const float* __restrict__ s2, const float* __restrict__ s3,
    const float* __restrict__ s4, const float* __restrict__ s5,
    u16* __restrict__ ws16) {
  constexpr int B1 = 393216, B2 = 2752512, B3 = 9830400,
                B4 = 16908288, B5 = 19267584, B6 = 21626880;
  int i = blockIdx.x * blockDim.x + threadIdx.x;
  int stride = gridDim.x * blockDim.x;
  for (; i < B6; i += stride) {
    const float* src; size_t off; u16* dst;
    if (i < B1)      { src = s0; off = i;      dst = ws16; }
    else if (i < B2) { src = s1; off = i - B1; dst = ws16 + 1572864; }
    else if (i < B3) { src = s2; off = i - B2; dst = ws16 + 11010048; }
    else if (i < B4) { src = s3; off = i - B3; dst = ws16 + 39321600; }
    else if (i < B5) { src = s4; off = i - B4; dst = ws16 + 67633152; }
    else             { src = s5; off = i - B5; dst = ws16 + 77070336; }
    float4 v = reinterpret_cast<const float4*>(src)[off];
    u16x4 o;
    o.x = f2bf(v.x); o.y = f2bf(v.y); o.z = f2bf(v.z); o.w = f2bf(v.w);
    reinterpret_cast<u16x4*>(dst)[off] = o;
  }
}

// ---------------- GEMM: m201-faithful 8-phase 256x256, BK=64 ----------------
// 512 thr = 8 waves (2M x 4N), wave tile 128x64. LDS [dbuf][mat][half] 16KB
// regions; half = 128 rows x 64 k (16 units of 1KB; unit = rowgrp*2+ks; byte
// = unit*1024 + lane*16 holds X[half*128+rowgrp*16+(lane&15)][ks*32+(lane>>4)*8..]).
// Per phase: {ds_read af (+bfr at quad 0) -> 2 stage glls -> BAR -> lgkm(0) ->
// setprio 16 MFMA -> vmcnt(8) -> BAR}. Stage schedule (iter t, phases 0..7):
//   ph0: kt 2t+1 A-g1 | ph1/2: kt 2t+2 B-h0/h1 | ph3/4: kt 2t+2 A-g0/g1
//   ph5/6: kt 2t+3 B-h0/h1 | ph7: kt 2t+3 A-g0
// Every staged region provably dead (B dies after its dbuf's quad0; A units
// 4q..4q+3 die after quad q). Every read's data staged >=5 pairs earlier ->
// per-phase vmcnt(8) (4 pairs in flight) suffices; final iter uses vmcnt(0).
// 2-D XCD chunk decode (FETCH 408->189 MB).
template <typename OT>
__global__ __launch_bounds__(512, 2) void gemm256(
    const u16* __restrict__ A,
    const u16* __restrict__ Bimg, const u16* __restrict__ Benc,
    const float* __restrict__ biasImg, const float* __restrict__ biasEnc,
    OT* __restrict__ Cimg, OT* __restrict__ Cenc,
    int N, int K, int split) {
  const int bid = blockIdx.x;
  const int ntn = N >> 8;
  const int CN = ntn >> 2;
  const int x = bid & 7, i5 = bid >> 3;
  const int mt = (x >> 2) * 7 + i5 / CN;
  const int nt = (x & 3) * CN + i5 % CN;
  const int m0 = mt << 8, n0 = nt << 8;
  const u16* B = (m0 < split) ? Benc : Bimg;
  const float* bias = (m0 < split) ? biasEnc : biasImg;

  __shared__ u16 lds[2][2][2][8192];  // [dbuf][A=0/B=1][half][16KB] = 128 KiB

  const int tid = threadIdx.x, w = tid >> 6, lane = tid & 63;
  const int wm = w >> 2, wn = w & 3;
  const int q = lane & 15, hi = lane >> 4;
  const size_t ldb = (size_t)K * 2;

  f32x4 acc[8][4];
#pragma unroll
  for (int i = 0; i < 8; ++i)
#pragma unroll
    for (int j = 0; j < 4; ++j)
#pragma unroll
      for (int r = 0; r < 4; ++r) acc[i][j][r] = 0.f;

  // stage pair: B half h of K-tile kt (2 glls: unit groups g=0,1)
  auto STG_B = [&](int kt, int h) {
    const int d = kt & 1;
    char* dst = (char*)&lds[d][1][h][0] + w * 1024 + lane * 16;
#pragma unroll
    for (int g = 0; g < 2; ++g) {
      const int n = g * 8 + w;
      const char* src = (const char*)B + (size_t)(n0 + h * 128 + (n >> 1) * 16 + q) * ldb
                        + (size_t)kt * 128 + (n & 1) * 64 + hi * 16;
      GLL16(src, dst + g * 8192);
    }
  };
  // stage pair: A unit-group g (both halves) of K-tile kt
  auto STG_A = [&](int kt, int g) {
    const int d = kt & 1;
#pragma unroll
    for (int h = 0; h < 2; ++h) {
      const int n = g * 8 + w;
      const char* src = (const char*)A + (size_t)(m0 + h * 128 + (n >> 1) * 16 + q) * ldb
                        + (size_t)kt * 128 + (n & 1) * 64 + hi * 16;
      GLL16(src, (char*)&lds[d][0][h][0] + n * 1024 + lane * 16);
    }
  };
  auto LDA = [&](int d, int i, int ks) -> bf16x8 {
    return *(const bf16x8*)((const char*)&lds[d][0][wm][0] + (i * 2 + ks) * 1024 + lane * 16);
  };
  auto LDB = [&](int d, int j, int ks) -> bf16x8 {
    return *(const bf16x8*)((const char*)&lds[d][1][wn >> 1][0]
                            + (((wn & 1) * 4 + j) * 2 + ks) * 1024 + lane * 16);
  };

  bf16x8 bfr[4][2];
  // one phase: quad ph of dbuf d; stageFn issues its 2 glls between reads & BAR
  auto PH = [&](int d, int ph, auto stageFn, bool last) {
    if (ph == 0) {
#pragma unroll
      for (int j = 0; j < 4; ++j)
#pragma unroll
        for (int ks = 0; ks < 2; ++ks) bfr[j][ks] = LDB(d, j, ks);
    }
    bf16x8 af[2][2];
#pragma unroll
    for (int m = 0; m < 2; ++m)
#pragma unroll
      for (int ks = 0; ks < 2; ++ks) af[m][ks] = LDA(d, 2 * ph + m, ks);
    stageFn();
    BAR();
    LGKM0();
    __builtin_amdgcn_s_setprio(1);
#pragma unroll
    for (int m = 0; m < 2; ++m)
#pragma unroll
      for (int j = 0; j < 4; ++j)
#pragma unroll
        for (int ks = 0; ks < 2; ++ks)
          acc[2 * ph + m][j] = __builtin_amdgcn_mfma_f32_16x16x32_bf16(
              af[m][ks], bfr[j][ks], acc[2 * ph + m][j], 0, 0, 0);
    __builtin_amdgcn_s_setprio(0);
    if (last) VMC0(); else VMC8();
    BAR();
  };

  const int NT2 = K >> 7;  // iterations of 2 K-tiles
  // prologue: 7 stage-pairs (kt0 full, kt1 all but A-g1)
  STG_B(0, 0); STG_B(0, 1); STG_A(0, 0); STG_A(0, 1);
  STG_B(1, 0); STG_B(1, 1); STG_A(1, 0);
  VMC8();   // 14 glls out -> oldest 6 landed (kt0 B + A-g0)
  BAR();
  for (int t = 0; t < NT2; ++t) {
    const bool full = (t + 1 < NT2);
    const bool last = (t == NT2 - 1);
    PH(0, 0, [&] { STG_A(2 * t + 1, 1); }, last);
    PH(0, 1, [&] { if (full) STG_B(2 * t + 2, 0); }, last);
    PH(0, 2, [&] { if (full) STG_B(2 * t + 2, 1); }, last);
    PH(0, 3, [&] { if (full) STG_A(2 * t + 2, 0); }, last);
    PH(1, 0, [&] { if (full) STG_A(2 * t + 2, 1); }, last);
    PH(1, 1, [&] { if (full) STG_B(2 * t + 3, 0); }, last);
    PH(1, 2, [&] { if (full) STG_B(2 * t + 3, 1); }, last);
    PH(1, 3, [&] { if (full) STG_A(2 * t + 3, 0); }, last);
  }

  // epilogue: row = m0 + wm*128 + i*16 + hi*4 + r,  col = n0 + wn*64 + j*16 + q
#pragma unroll
  for (int i = 0; i < 8; ++i) {
    int rbase = m0 + wm * 128 + i * 16 + (hi << 2);
#pragma unroll
    for (int j = 0; j < 4; ++j) {
      int col = n0 + wn * 64 + j * 16 + q;
      float bv = bias ? bias[col] : 0.f;
#pragma unroll
      for (int r = 0; r < 4; ++r) {
        int row = rbase + r;
        float v = acc[i][j][r] + bv;
        if (row < split) store_out(&Cenc[(size_t)row * N + col], v);
        else             store_out(&Cimg[(size_t)(row - split) * N + col], v);
      }
    }
  }
}

// ---------------- per-head RMSnorm(q,k) + RoPE(q,k), emit V^T -----------------
// Q pre-scaled by log2(e)/sqrt(128) so attn scores land in log2 units.
__global__ __launch_bounds__(256) void norm_rope(
    u16* __restrict__ qkv, u16* __restrict__ vt,
    const float* __restrict__ cosT, const float* __restrict__ sinT,
    const float* __restrict__ nqw_img, const float* __restrict__ nkw_img,
    const float* __restrict__ nqw_enc, const float* __restrict__ nkw_enc) {
  const int h = blockIdx.y;
  const int s0 = blockIdx.x * 64;
  const int tid = threadIdx.x, w = tid >> 6, lane = tid & 63;
  const bool enc = (s0 < 512);
  const float* nqw = enc ? nqw_enc : nqw_img;
  const float* nkw = enc ? nkw_enc : nkw_img;
  const float SCL = 0.12751743f;  // log2(e)/sqrt(128)
  const float wq0 = nqw[2 * lane], wq1 = nqw[2 * lane + 1];
  const float wk0 = nkw[2 * lane], wk1 = nkw[2 * lane + 1];
  u16x8 va0, va1, vb0, vb1;
#pragma unroll
  for (int r = 0; r < 16; ++r) {
    const int s = s0 + w * 16 + r;
    const size_t rowb = (size_t)s * 9216 + h * 128 + 2 * lane;
    float2 cv = *(const float2*)&cosT[(size_t)s * 128 + 2 * lane];
    float2 sv = *(const float2*)&sinT[(size_t)s * 128 + 2 * lane];
    {  // Q
      u16x2 qu = *(u16x2*)&qkv[rowb];
      float x0 = bf2f(qu.x), x1 = bf2f(qu.y);
      float ss = x0 * x0 + x1 * x1;
#pragma unroll
      for (int d = 1; d < 64; d <<= 1) ss += __shfl_xor(ss, d);
      float rms = rsqrtf(ss * (1.0f / 128.0f) + 1e-5f);
      x0 *= rms * wq0; x1 *= rms * wq1;
      float o0 = (x0 * cv.x - x1 * sv.x) * SCL;
      float o1 = (x1 * cv.y + x0 * sv.y) * SCL;
      u16x2 ou; ou.x = f2bf(o0); ou.y = f2bf(o1);
      *(u16x2*)&qkv[rowb] = ou;
    }
    {  // K
      u16x2 ku = *(u16x2*)&qkv[rowb + 3072];
      float x0 = bf2f(ku.x), x1 = bf2f(ku.y);
      float ss = x0 * x0 + x1 * x1;
#pragma unroll
      for (int d = 1; d < 64; d <<= 1) ss += __shfl_xor(ss, d);
      float rms = rsqrtf(ss * (1.0f / 128.0f) + 1e-5f);
      x0 *= rms * wk0; x1 *= rms * wk1;
      float o0 = x0 * cv.x - x1 * sv.x;
      float o1 = x1 * cv.y + x0 * sv.y;
      u16x2 ou; ou.x = f2bf(o0); ou.y = f2bf(o1);
      *(u16x2*)&qkv[rowb + 3072] = ou;
    }
    {  // V -> registers for transposed store
      u16x2 vu = *(u16x2*)&qkv[rowb + 6144];
      if (r < 8) { va0[r] = vu.x; vb0[r] = vu.y; }
      else       { va1[r - 8] = vu.x; vb1[r - 8] = vu.y; }
    }
  }
  const size_t vbase = (size_t)h * 128 * 3584 + (size_t)(2 * lane) * 3584 + s0 + w * 16;
  *(u16x8*)&vt[vbase]            = va0;
  *(u16x8*)&vt[vbase + 8]        = va1;
  *(u16x8*)&vt[vbase + 3584]     = vb0;
  *(u16x8*)&vt[vbase + 3584 + 8] = vb1;
}

// ---------------- flash attention (32x32 MFMA, in-reg P, KVBLK=32, 3-buf) ---
// (unchanged from R14 — 3 rotating buffers, 1 barrier/tile, vmcnt(8))
__global__ __launch_bounds__(256, 2) void attn_kernel(
    const u16* __restrict__ qkv, const u16* __restrict__ vt,
    u16* __restrict__ aout) {
  const int bid = blockIdx.x;
  const int qt = bid / 24;
  const int rr = bid % 24;
  const int h = (rr % 8) * 3 + (rr / 8);
  const int tid = threadIdx.x, w = tid >> 6, lane = tid & 63;
  const int q32 = lane & 31, hi5 = lane >> 5;
  const int qbase = qt * 128 + w * 32;
  __shared__ u16 Klds[3][4096];
  __shared__ u16 Vlds[3][4096];

  bf16x8 aq[8];
  {
    const u16* qp = qkv + (size_t)(qbase + q32) * 9216 + h * 128 + hi5 * 8;
#pragma unroll
    for (int ds = 0; ds < 8; ++ds) aq[ds] = *(const bf16x8*)(qp + ds * 16);
  }
  float m_i = -1e30f, l_i = 0.f;
  f32x16 o[4];
#pragma unroll
  for (int dt = 0; dt < 4; ++dt)
#pragma unroll
    for (int r = 0; r < 16; ++r) o[dt][r] = 0.f;
  const size_t vhead = (size_t)h * 128 * 3584;

  auto STAGE_K = [&](int kt0, int b) {
    const char* src = (const char*)(qkv + (size_t)(kt0 + q32) * 9216 + 3072 + h * 128) + hi5 * 16;
    char* dst = (char*)Klds[b] + w * 2048 + lane * 16;
#pragma unroll
    for (int j = 0; j < 2; ++j)
      GLL16(src + (w * 2 + j) * 32, dst + j * 1024);
  };
  auto STAGE_V = [&](int kt0, int b) {
    char* dst = (char*)Vlds[b] + w * 2048 + lane * 16;
#pragma unroll
    for (int j = 0; j < 2; ++j) {
      const int u = w * 2 + j, dt = u >> 1, ks = u & 1;
      GLL16((const char*)(vt + vhead + (size_t)(dt * 32 + q32) * 3584 + kt0) + ks * 32 + hi5 * 16,
            dst + j * 1024);
    }
  };

  auto PACK = [&](const float* p, bf16x8* out2) {
    unsigned w0[4], w1[4];
#pragma unroll
    for (int g = 0; g < 4; ++g) {
      asm("v_cvt_pk_bf16_f32 %0, %1, %2" : "=v"(w0[g]) : "v"(p[4 * g + 0]), "v"(p[4 * g + 1]));
      asm("v_cvt_pk_bf16_f32 %0, %1, %2" : "=v"(w1[g]) : "v"(p[4 * g + 2]), "v"(p[4 * g + 3]));
    }
    asm("v_permlane32_swap_b32 %0, %1" : "+v"(w0[0]), "+v"(w0[1]));
    asm("v_permlane32_swap_b32 %0, %1" : "+v"(w1[0]), "+v"(w1[1]));
    asm("v_permlane32_swap_b32 %0, %1" : "+v"(w0[2]), "+v"(w0[3]));
    asm("v_permlane32_swap_b32 %0, %1" : "+v"(w1[2]), "+v"(w1[3]));
    u32x4 lo = {w0[0], w1[0], w0[1], w1[1]};
    u32x4 hi_ = {w0[2], w1[2], w0[3], w1[3]};
    out2[0] = __builtin_bit_cast(bf16x8, lo);
    out2[1] = __builtin_bit_cast(bf16x8, hi_);
  };

  const int NT = 112;
  STAGE_K(0, 0);   STAGE_V(0, 0);
  STAGE_K(32, 1);  STAGE_V(32, 1);
  int cur = 0;
  for (int t = 0; t < NT; ++t) {
    if (t + 1 < NT) VMC8(); else VMC0();
    BAR();

    f32x16 s0;
#pragma unroll
    for (int r = 0; r < 16; ++r) s0[r] = 0.f;
    __builtin_amdgcn_s_setprio(1);
#pragma unroll
    for (int ds = 0; ds < 8; ++ds) {
      bf16x8 k0 = *(const bf16x8*)((const char*)Klds[cur] + ds * 1024 + lane * 16);
      s0 = __builtin_amdgcn_mfma_f32_32x32x16_bf16(k0, aq[ds], s0, 0, 0, 0);
    }
    __builtin_amdgcn_s_setprio(0);

    float mx = s0[0];
#pragma unroll
    for (int r = 1; r < 16; ++r) mx = fmaxf(mx, s0[r]);
    mx = fmaxf(mx, __shfl_xor(mx, 32));
    if (!__all(mx - m_i <= 8.f)) {
      float mnew = fmaxf(m_i, mx);
      float alpha = __builtin_amdgcn_exp2f(m_i - mnew);
      m_i = mnew;
      l_i *= alpha;
#pragma unroll
      for (int r = 0; r < 16; ++r) {
        int qr = (r & 3) + 8 * (r >> 2) + 4 * hi5;
        float ar = __shfl(alpha, qr);
#pragma unroll
        for (int dt = 0; dt < 4; ++dt) o[dt][r] *= ar;
      }
    }
    float p0[16];
    float psum = 0.f;
#pragma unroll
    for (int r = 0; r < 16; ++r) { p0[r] = __builtin_amdgcn_exp2f(s0[r] - m_i); psum += p0[r]; }
    psum += __shfl_xor(psum, 32);
    l_i += psum;

    bf16x8 pa[2];
    PACK(p0, pa);

    __builtin_amdgcn_s_setprio(1);
#pragma unroll
    for (int dt = 0; dt < 4; ++dt) {
#pragma unroll
      for (int ks = 0; ks < 2; ++ks) {
        bf16x8 bv = *(const bf16x8*)((const char*)Vlds[cur] + (dt * 2 + ks) * 1024 + lane * 16);
        o[dt] = __builtin_amdgcn_mfma_f32_32x32x16_bf16(pa[ks], bv, o[dt], 0, 0, 0);
      }
    }
    __builtin_amdgcn_s_setprio(0);

    if (t + 2 < NT) {
      const int stg = cur ? cur - 1 : 2;
      STAGE_K((t + 2) * 32, stg);
      STAGE_V((t + 2) * 32, stg);
    }
    cur = (cur == 2) ? 0 : cur + 1;
  }

#pragma unroll
  for (int r = 0; r < 16; ++r) {
    const int qr = (r & 3) + 8 * (r >> 2) + 4 * hi5;
    const float lr = __shfl(l_i, qr);
    const float inv = 1.0f / lr;
    const size_t srow = (size_t)(qbase + qr) * 3072 + h * 128 + q32;
#pragma unroll
    for (int dt = 0; dt < 4; ++dt)
      aout[srow + dt * 32] = f2bf(o[dt][r] * inv);
  }
}

extern "C" void kernel_launch(void* const* d_in, const int* in_sizes, int n_in,
                              void* d_out, int out_size, void* d_ws, size_t ws_size,
                              hipStream_t stream) {
  (void)in_sizes; (void)n_in; (void)out_size; (void)ws_size;
  const float* hs    = (const float*)d_in[0];
  const float* ehs   = (const float*)d_in[1];
  const float* cosT  = (const float*)d_in[2];
  const float* sinT  = (const float*)d_in[3];
  const float* Wqkv  = (const float*)d_in[4];
  const float* Wadd  = (const float*)d_in[5];
  const float* bAdd  = (const float*)d_in[6];
  const float* nqw   = (const float*)d_in[7];
  const float* nkw   = (const float*)d_in[8];
  const float* naqw  = (const float*)d_in[9];
  const float* nakw  = (const float*)d_in[10];
  const float* Wout  = (const float*)d_in[11];
  const float* bout  = (const float*)d_in[12];
  const float* Waddo = (const float*)d_in[13];
  const float* baddo = (const float*)d_in[14];

  char* ws = (char*)d_ws;
  u16* Ain = (u16*)(ws);                       // [3584][3072]
  u16* WqI = (u16*)(ws + 22020096);            // [9216][3072]
  u16* WqE = WqI + (size_t)9216 * 3072;
  u16* WoI = (u16*)(ws + 135266304);           // [3072][3072]
  u16* WoE = WoI + (size_t)3072 * 3072;
  u16* qkv = (u16*)(ws + 173015040);           // [3584][9216]
  u16* vt   = Ain;  // alias: A_in dead after QKV GEMM
  u16* aout = WqI;  // alias: W_qkv dead after QKV GEMM

  cvt_all<<<4096, 256, 0, stream>>>(ehs, hs, Wqkv, Wadd, Wout, Waddo, (u16*)ws);

  gemm256<u16><<<dim3(504), 512, 0, stream>>>(Ain, WqI, WqE, nullptr, bAdd,
                                              qkv + (size_t)512 * 9216, qkv, 9216, 3072, 512);
  norm_rope<<<dim3(56, 24), 256, 0, stream>>>(qkv, vt, cosT, sinT, nqw, nkw, naqw, nakw);
  attn_kernel<<<dim3(672), 256, 0, stream>>>(qkv, vt, aout);
  float* outp = (float*)d_out;
  gemm256<float><<<dim3(168), 512, 0, stream>>>(aout, WoI, WoE, bout, baddo,
                                                outp, outp + (size_t)3072 * 3072, 3072, 3072, 512);
}

// Round 16
// 623.912 us; speedup vs baseline: 1.0666x; 1.0005x over previous
//
#include <hip/hip_runtime.h>

// Flux2 double-stream attention block, bf16 MFMA pipeline, f32 final output.
// Stages: fused cvt(f32->bf16) -> QKV GEMM (8-phase 256^2, LDS-BW-bound at
//         ~875 TF — 5 schedule variants identical, see R15 post-mortem) ->
//         RMSnorm+RoPE(+V^T) -> flash attn (3-buf, 3 blocks/CU) -> out GEMM.
// ws layout (bytes):
//   [0,           22020096)  A_in bf16 [3584][3072]   } later aliased by V^T [24][128][3584]
//   [22020096,   135266304)  Wq bf16: img [9216][3072] then enc } later aliased by attn_out
//   [135266304,  173015040)  Wo bf16: img [3072][3072] then enc
//   [173015040,  239075328)  qkv bf16 [3584][9216]
// peak ws = 239,075,328 B.

typedef unsigned short u16;
typedef __attribute__((ext_vector_type(2))) unsigned short u16x2;
typedef __attribute__((ext_vector_type(4))) unsigned short u16x4;
typedef __attribute__((ext_vector_type(8))) unsigned short u16x8;
typedef __attribute__((ext_vector_type(8))) short bf16x8;
typedef __attribute__((ext_vector_type(4))) float f32x4;
typedef __attribute__((ext_vector_type(16))) float f32x16;
typedef __attribute__((ext_vector_type(4))) unsigned u32x4;

#define DEV __device__ __forceinline__

DEV u16 f2bf(float f) {
  unsigned u = __builtin_bit_cast(unsigned, f);
  u = (u + 0x7FFFu + ((u >> 16) & 1u)) >> 16;   // RNE
  return (u16)u;
}
DEV float bf2f(u16 s) { return __builtin_bit_cast(float, (unsigned)s << 16); }

DEV void store_out(u16* p, float v)  { *p = f2bf(v); }
DEV void store_out(float* p, float v) { *p = v; }

#define AS1(p) (const __attribute__((address_space(1))) void*)(p)
#define AS3(p) (__attribute__((address_space(3))) void*)(p)
#define GLL16(g, l) __builtin_amdgcn_global_load_lds(AS1(g), AS3(l), 16, 0, 0)

#define BAR() do { asm volatile("" ::: "memory"); __builtin_amdgcn_s_barrier(); \
                   asm volatile("" ::: "memory"); } while (0)
#define LGKM0() asm volatile("s_waitcnt lgkmcnt(0)" ::: "memory")
#define VMC8() asm volatile("s_waitcnt vmcnt(8)" ::: "memory")
#define VMC0() asm volatile("s_waitcnt vmcnt(0)" ::: "memory")

// ---------------- fused fp32 -> bf16 convert (6 segments, 1 dispatch) -------
__global__ __launch_bounds__(256) void cvt_all(
    const float* __restrict__ s0, const float* __restrict__ s1,
    const float* __restrict__ s2, const float* __restrict__ s3,
    const float* __restrict__ s4, const float* __restrict__ s5,
    u16* __restrict__ ws16) {
  constexpr int B1 = 393216, B2 = 2752512, B3 = 9830400,
                B4 = 16908288, B5 = 19267584, B6 = 21626880;
  int i = blockIdx.x * blockDim.x + threadIdx.x;
  int stride = gridDim.x * blockDim.x;
  for (; i < B6; i += stride) {
    const float* src; size_t off; u16* dst;
    if (i < B1)      { src = s0; off = i;      dst = ws16; }
    else if (i < B2) { src = s1; off = i - B1; dst = ws16 + 1572864; }
    else if (i < B3) { src = s2; off = i - B2; dst = ws16 + 11010048; }
    else if (i < B4) { src = s3; off = i - B3; dst = ws16 + 39321600; }
    else if (i < B5) { src = s4; off = i - B4; dst = ws16 + 67633152; }
    else             { src = s5; off = i - B5; dst = ws16 + 77070336; }
    float4 v = reinterpret_cast<const float4*>(src)[off];
    u16x4 o;
    o.x = f2bf(v.x); o.y = f2bf(v.y); o.z = f2bf(v.z); o.w = f2bf(v.w);
    reinterpret_cast<u16x4*>(dst)[off] = o;
  }
}

// ---------------- GEMM: 8-phase 256x256, BK=64 (R15 form, kept) -------------
// LDS-BW-bound at ~875 TF / 37% MfmaUtil: per K-tile per CU, 192 ds_read_b128
// (0.375 reads/MFMA, A-half shared by 4 waves) saturates the LDS pipe before
// the MFMA pipe. Five schedule variants (R10-R15) measured identical.
template <typename OT>
__global__ __launch_bounds__(512, 2) void gemm256(
    const u16* __restrict__ A,
    const u16* __restrict__ Bimg, const u16* __restrict__ Benc,
    const float* __restrict__ biasImg, const float* __restrict__ biasEnc,
    OT* __restrict__ Cimg, OT* __restrict__ Cenc,
    int N, int K, int split) {
  const int bid = blockIdx.x;
  const int ntn = N >> 8;
  const int CN = ntn >> 2;
  const int x = bid & 7, i5 = bid >> 3;
  const int mt = (x >> 2) * 7 + i5 / CN;
  const int nt = (x & 3) * CN + i5 % CN;
  const int m0 = mt << 8, n0 = nt << 8;
  const u16* B = (m0 < split) ? Benc : Bimg;
  const float* bias = (m0 < split) ? biasEnc : biasImg;

  __shared__ u16 lds[2][2][2][8192];  // [dbuf][A=0/B=1][half][16KB] = 128 KiB

  const int tid = threadIdx.x, w = tid >> 6, lane = tid & 63;
  const int wm = w >> 2, wn = w & 3;
  const int q = lane & 15, hi = lane >> 4;
  const size_t ldb = (size_t)K * 2;

  f32x4 acc[8][4];
#pragma unroll
  for (int i = 0; i < 8; ++i)
#pragma unroll
    for (int j = 0; j < 4; ++j)
#pragma unroll
      for (int r = 0; r < 4; ++r) acc[i][j][r] = 0.f;

  auto STG_B = [&](int kt, int h) {
    const int d = kt & 1;
    char* dst = (char*)&lds[d][1][h][0] + w * 1024 + lane * 16;
#pragma unroll
    for (int g = 0; g < 2; ++g) {
      const int n = g * 8 + w;
      const char* src = (const char*)B + (size_t)(n0 + h * 128 + (n >> 1) * 16 + q) * ldb
                        + (size_t)kt * 128 + (n & 1) * 64 + hi * 16;
      GLL16(src, dst + g * 8192);
    }
  };
  auto STG_A = [&](int kt, int g) {
    const int d = kt & 1;
#pragma unroll
    for (int h = 0; h < 2; ++h) {
      const int n = g * 8 + w;
      const char* src = (const char*)A + (size_t)(m0 + h * 128 + (n >> 1) * 16 + q) * ldb
                        + (size_t)kt * 128 + (n & 1) * 64 + hi * 16;
      GLL16(src, (char*)&lds[d][0][h][0] + n * 1024 + lane * 16);
    }
  };
  auto LDA = [&](int d, int i, int ks) -> bf16x8 {
    return *(const bf16x8*)((const char*)&lds[d][0][wm][0] + (i * 2 + ks) * 1024 + lane * 16);
  };
  auto LDB = [&](int d, int j, int ks) -> bf16x8 {
    return *(const bf16x8*)((const char*)&lds[d][1][wn >> 1][0]
                            + (((wn & 1) * 4 + j) * 2 + ks) * 1024 + lane * 16);
  };

  bf16x8 bfr[4][2];
  auto PH = [&](int d, int ph, auto stageFn, bool last) {
    if (ph == 0) {
#pragma unroll
      for (int j = 0; j < 4; ++j)
#pragma unroll
        for (int ks = 0; ks < 2; ++ks) bfr[j][ks] = LDB(d, j, ks);
    }
    bf16x8 af[2][2];
#pragma unroll
    for (int m = 0; m < 2; ++m)
#pragma unroll
      for (int ks = 0; ks < 2; ++ks) af[m][ks] = LDA(d, 2 * ph + m, ks);
    stageFn();
    BAR();
    LGKM0();
    __builtin_amdgcn_s_setprio(1);
#pragma unroll
    for (int m = 0; m < 2; ++m)
#pragma unroll
      for (int j = 0; j < 4; ++j)
#pragma unroll
        for (int ks = 0; ks < 2; ++ks)
          acc[2 * ph + m][j] = __builtin_amdgcn_mfma_f32_16x16x32_bf16(
              af[m][ks], bfr[j][ks], acc[2 * ph + m][j], 0, 0, 0);
    __builtin_amdgcn_s_setprio(0);
    if (last) VMC0(); else VMC8();
    BAR();
  };

  const int NT2 = K >> 7;
  STG_B(0, 0); STG_B(0, 1); STG_A(0, 0); STG_A(0, 1);
  STG_B(1, 0); STG_B(1, 1); STG_A(1, 0);
  VMC8();
  BAR();
  for (int t = 0; t < NT2; ++t) {
    const bool full = (t + 1 < NT2);
    const bool last = (t == NT2 - 1);
    PH(0, 0, [&] { STG_A(2 * t + 1, 1); }, last);
    PH(0, 1, [&] { if (full) STG_B(2 * t + 2, 0); }, last);
    PH(0, 2, [&] { if (full) STG_B(2 * t + 2, 1); }, last);
    PH(0, 3, [&] { if (full) STG_A(2 * t + 2, 0); }, last);
    PH(1, 0, [&] { if (full) STG_A(2 * t + 2, 1); }, last);
    PH(1, 1, [&] { if (full) STG_B(2 * t + 3, 0); }, last);
    PH(1, 2, [&] { if (full) STG_B(2 * t + 3, 1); }, last);
    PH(1, 3, [&] { if (full) STG_A(2 * t + 3, 0); }, last);
  }

#pragma unroll
  for (int i = 0; i < 8; ++i) {
    int rbase = m0 + wm * 128 + i * 16 + (hi << 2);
#pragma unroll
    for (int j = 0; j < 4; ++j) {
      int col = n0 + wn * 64 + j * 16 + q;
      float bv = bias ? bias[col] : 0.f;
#pragma unroll
      for (int r = 0; r < 4; ++r) {
        int row = rbase + r;
        float v = acc[i][j][r] + bv;
        if (row < split) store_out(&Cenc[(size_t)row * N + col], v);
        else             store_out(&Cimg[(size_t)(row - split) * N + col], v);
      }
    }
  }
}

// ---------------- per-head RMSnorm(q,k) + RoPE(q,k), emit V^T -----------------
// Q pre-scaled by log2(e)/sqrt(128) so attn scores land in log2 units.
__global__ __launch_bounds__(256) void norm_rope(
    u16* __restrict__ qkv, u16* __restrict__ vt,
    const float* __restrict__ cosT, const float* __restrict__ sinT,
    const float* __restrict__ nqw_img, const float* __restrict__ nkw_img,
    const float* __restrict__ nqw_enc, const float* __restrict__ nkw_enc) {
  const int h = blockIdx.y;
  const int s0 = blockIdx.x * 64;
  const int tid = threadIdx.x, w = tid >> 6, lane = tid & 63;
  const bool enc = (s0 < 512);
  const float* nqw = enc ? nqw_enc : nqw_img;
  const float* nkw = enc ? nkw_enc : nkw_img;
  const float SCL = 0.12751743f;  // log2(e)/sqrt(128)
  const float wq0 = nqw[2 * lane], wq1 = nqw[2 * lane + 1];
  const float wk0 = nkw[2 * lane], wk1 = nkw[2 * lane + 1];
  u16x8 va0, va1, vb0, vb1;
#pragma unroll
  for (int r = 0; r < 16; ++r) {
    const int s = s0 + w * 16 + r;
    const size_t rowb = (size_t)s * 9216 + h * 128 + 2 * lane;
    float2 cv = *(const float2*)&cosT[(size_t)s * 128 + 2 * lane];
    float2 sv = *(const float2*)&sinT[(size_t)s * 128 + 2 * lane];
    {  // Q
      u16x2 qu = *(u16x2*)&qkv[rowb];
      float x0 = bf2f(qu.x), x1 = bf2f(qu.y);
      float ss = x0 * x0 + x1 * x1;
#pragma unroll
      for (int d = 1; d < 64; d <<= 1) ss += __shfl_xor(ss, d);
      float rms = rsqrtf(ss * (1.0f / 128.0f) + 1e-5f);
      x0 *= rms * wq0; x1 *= rms * wq1;
      float o0 = (x0 * cv.x - x1 * sv.x) * SCL;
      float o1 = (x1 * cv.y + x0 * sv.y) * SCL;
      u16x2 ou; ou.x = f2bf(o0); ou.y = f2bf(o1);
      *(u16x2*)&qkv[rowb] = ou;
    }
    {  // K
      u16x2 ku = *(u16x2*)&qkv[rowb + 3072];
      float x0 = bf2f(ku.x), x1 = bf2f(ku.y);
      float ss = x0 * x0 + x1 * x1;
#pragma unroll
      for (int d = 1; d < 64; d <<= 1) ss += __shfl_xor(ss, d);
      float rms = rsqrtf(ss * (1.0f / 128.0f) + 1e-5f);
      x0 *= rms * wk0; x1 *= rms * wk1;
      float o0 = x0 * cv.x - x1 * sv.x;
      float o1 = x1 * cv.y + x0 * sv.y;
      u16x2 ou; ou.x = f2bf(o0); ou.y = f2bf(o1);
      *(u16x2*)&qkv[rowb + 3072] = ou;
    }
    {  // V -> registers for transposed store
      u16x2 vu = *(u16x2*)&qkv[rowb + 6144];
      if (r < 8) { va0[r] = vu.x; vb0[r] = vu.y; }
      else       { va1[r - 8] = vu.x; vb1[r - 8] = vu.y; }
    }
  }
  const size_t vbase = (size_t)h * 128 * 3584 + (size_t)(2 * lane) * 3584 + s0 + w * 16;
  *(u16x8*)&vt[vbase]            = va0;
  *(u16x8*)&vt[vbase + 8]        = va1;
  *(u16x8*)&vt[vbase + 3584]     = vb0;
  *(u16x8*)&vt[vbase + 3584 + 8] = vb1;
}

// ---------------- flash attention (32x32 MFMA, in-reg P, KVBLK=32, 3-buf) ---
// R16: launch_bounds (256,2) -> (256,3). LDS 48 KB allows 3 blocks/CU
// (3x48=144 <= 160); register budget: ~112 arch + 64 AGPR acc ~= 176 vs the
// 170/wave cap at 3 waves/SIMD — close; spill signature = WRITE_SIZE >> 21.5MB
// (R9 lesson). If clean: all 672 blocks co-resident (768 slots) -> no
// scheduler tail + 3 waves/SIMD to overlap the serial QK->SM->PACK->PV chain.
__global__ __launch_bounds__(256, 3) void attn_kernel(
    const u16* __restrict__ qkv, const u16* __restrict__ vt,
    u16* __restrict__ aout) {
  const int bid = blockIdx.x;
  const int qt = bid / 24;
  const int rr = bid % 24;
  const int h = (rr % 8) * 3 + (rr / 8);
  const int tid = threadIdx.x, w = tid >> 6, lane = tid & 63;
  const int q32 = lane & 31, hi5 = lane >> 5;
  const int qbase = qt * 128 + w * 32;
  __shared__ u16 Klds[3][4096];
  __shared__ u16 Vlds[3][4096];

  bf16x8 aq[8];
  {
    const u16* qp = qkv + (size_t)(qbase + q32) * 9216 + h * 128 + hi5 * 8;
#pragma unroll
    for (int ds = 0; ds < 8; ++ds) aq[ds] = *(const bf16x8*)(qp + ds * 16);
  }
  float m_i = -1e30f, l_i = 0.f;
  f32x16 o[4];
#pragma unroll
  for (int dt = 0; dt < 4; ++dt)
#pragma unroll
    for (int r = 0; r < 16; ++r) o[dt][r] = 0.f;
  const size_t vhead = (size_t)h * 128 * 3584;

  auto STAGE_K = [&](int kt0, int b) {
    const char* src = (const char*)(qkv + (size_t)(kt0 + q32) * 9216 + 3072 + h * 128) + hi5 * 16;
    char* dst = (char*)Klds[b] + w * 2048 + lane * 16;
#pragma unroll
    for (int j = 0; j < 2; ++j)
      GLL16(src + (w * 2 + j) * 32, dst + j * 1024);
  };
  auto STAGE_V = [&](int kt0, int b) {
    char* dst = (char*)Vlds[b] + w * 2048 + lane * 16;
#pragma unroll
    for (int j = 0; j < 2; ++j) {
      const int u = w * 2 + j, dt = u >> 1, ks = u & 1;
      GLL16((const char*)(vt + vhead + (size_t)(dt * 32 + q32) * 3584 + kt0) + ks * 32 + hi5 * 16,
            dst + j * 1024);
    }
  };

  auto PACK = [&](const float* p, bf16x8* out2) {
    unsigned w0[4], w1[4];
#pragma unroll
    for (int g = 0; g < 4; ++g) {
      asm("v_cvt_pk_bf16_f32 %0, %1, %2" : "=v"(w0[g]) : "v"(p[4 * g + 0]), "v"(p[4 * g + 1]));
      asm("v_cvt_pk_bf16_f32 %0, %1, %2" : "=v"(w1[g]) : "v"(p[4 * g + 2]), "v"(p[4 * g + 3]));
    }
    asm("v_permlane32_swap_b32 %0, %1" : "+v"(w0[0]), "+v"(w0[1]));
    asm("v_permlane32_swap_b32 %0, %1" : "+v"(w1[0]), "+v"(w1[1]));
    asm("v_permlane32_swap_b32 %0, %1" : "+v"(w0[2]), "+v"(w0[3]));
    asm("v_permlane32_swap_b32 %0, %1" : "+v"(w1[2]), "+v"(w1[3]));
    u32x4 lo = {w0[0], w1[0], w0[1], w1[1]};
    u32x4 hi_ = {w0[2], w1[2], w0[3], w1[3]};
    out2[0] = __builtin_bit_cast(bf16x8, lo);
    out2[1] = __builtin_bit_cast(bf16x8, hi_);
  };

  const int NT = 112;
  STAGE_K(0, 0);   STAGE_V(0, 0);
  STAGE_K(32, 1);  STAGE_V(32, 1);
  int cur = 0;
  for (int t = 0; t < NT; ++t) {
    if (t + 1 < NT) VMC8(); else VMC0();
    BAR();

    f32x16 s0;
#pragma unroll
    for (int r = 0; r < 16; ++r) s0[r] = 0.f;
    __builtin_amdgcn_s_setprio(1);
#pragma unroll
    for (int ds = 0; ds < 8; ++ds) {
      bf16x8 k0 = *(const bf16x8*)((const char*)Klds[cur] + ds * 1024 + lane * 16);
      s0 = __builtin_amdgcn_mfma_f32_32x32x16_bf16(k0, aq[ds], s0, 0, 0, 0);
    }
    __builtin_amdgcn_s_setprio(0);

    float mx = s0[0];
#pragma unroll
    for (int r = 1; r < 16; ++r) mx = fmaxf(mx, s0[r]);
    mx = fmaxf(mx, __shfl_xor(mx, 32));
    if (!__all(mx - m_i <= 8.f)) {
      float mnew = fmaxf(m_i, mx);
      float alpha = __builtin_amdgcn_exp2f(m_i - mnew);
      m_i = mnew;
      l_i *= alpha;
#pragma unroll
      for (int r = 0; r < 16; ++r) {
        int qr = (r & 3) + 8 * (r >> 2) + 4 * hi5;
        float ar = __shfl(alpha, qr);
#pragma unroll
        for (int dt = 0; dt < 4; ++dt) o[dt][r] *= ar;
      }
    }
    float p0[16];
    float psum = 0.f;
#pragma unroll
    for (int r = 0; r < 16; ++r) { p0[r] = __builtin_amdgcn_exp2f(s0[r] - m_i); psum += p0[r]; }
    psum += __shfl_xor(psum, 32);
    l_i += psum;

    bf16x8 pa[2];
    PACK(p0, pa);

    __builtin_amdgcn_s_setprio(1);
#pragma unroll
    for (int dt = 0; dt < 4; ++dt) {
#pragma unroll
      for (int ks = 0; ks < 2; ++ks) {
        bf16x8 bv = *(const bf16x8*)((const char*)Vlds[cur] + (dt * 2 + ks) * 1024 + lane * 16);
        o[dt] = __builtin_amdgcn_mfma_f32_32x32x16_bf16(pa[ks], bv, o[dt], 0, 0, 0);
      }
    }
    __builtin_amdgcn_s_setprio(0);

    if (t + 2 < NT) {
      const int stg = cur ? cur - 1 : 2;
      STAGE_K((t + 2) * 32, stg);
      STAGE_V((t + 2) * 32, stg);
    }
    cur = (cur == 2) ? 0 : cur + 1;
  }

#pragma unroll
  for (int r = 0; r < 16; ++r) {
    const int qr = (r & 3) + 8 * (r >> 2) + 4 * hi5;
    const float lr = __shfl(l_i, qr);
    const float inv = 1.0f / lr;
    const size_t srow = (size_t)(qbase + qr) * 3072 + h * 128 + q32;
#pragma unroll
    for (int dt = 0; dt < 4; ++dt)
      aout[srow + dt * 32] = f2bf(o[dt][r] * inv);
  }
}

extern "C" void kernel_launch(void* const* d_in, const int* in_sizes, int n_in,
                              void* d_out, int out_size, void* d_ws, size_t ws_size,
                              hipStream_t stream) {
  (void)in_sizes; (void)n_in; (void)out_size; (void)ws_size;
  const float* hs    = (const float*)d_in[0];
  const float* ehs   = (const float*)d_in[1];
  const float* cosT  = (const float*)d_in[2];
  const float* sinT  = (const float*)d_in[3];
  const float* Wqkv  = (const float*)d_in[4];
  const float* Wadd  = (const float*)d_in[5];
  const float* bAdd  = (const float*)d_in[6];
  const float* nqw   = (const float*)d_in[7];
  const float* nkw   = (const float*)d_in[8];
  const float* naqw  = (const float*)d_in[9];
  const float* nakw  = (const float*)d_in[10];
  const float* Wout  = (const float*)d_in[11];
  const float* bout  = (const float*)d_in[12];
  const float* Waddo = (const float*)d_in[13];
  const float* baddo = (const float*)d_in[14];

  char* ws = (char*)d_ws;
  u16* Ain = (u16*)(ws);                       // [3584][3072]
  u16* WqI = (u16*)(ws + 22020096);            // [9216][3072]
  u16* WqE = WqI + (size_t)9216 * 3072;
  u16* WoI = (u16*)(ws + 135266304);           // [3072][3072]
  u16* WoE = WoI + (size_t)3072 * 3072;
  u16* qkv = (u16*)(ws + 173015040);           // [3584][9216]
  u16* vt   = Ain;  // alias: A_in dead after QKV GEMM
  u16* aout = WqI;  // alias: W_qkv dead after QKV GEMM

  cvt_all<<<4096, 256, 0, stream>>>(ehs, hs, Wqkv, Wadd, Wout, Waddo, (u16*)ws);

  gemm256<u16><<<dim3(504), 512, 0, stream>>>(Ain, WqI, WqE, nullptr, bAdd,
                                              qkv + (size_t)512 * 9216, qkv, 9216, 3072, 512);
  norm_rope<<<dim3(56, 24), 256, 0, stream>>>(qkv, vt, cosT, sinT, nqw, nkw, naqw, nakw);
  attn_kernel<<<dim3(672), 256, 0, stream>>>(qkv, vt, aout);
  float* outp = (float*)d_out;
  gemm256<float><<<dim3(168), 512, 0, stream>>>(aout, WoI, WoE, bout, baddo,
                                                outp, outp + (size_t)3072 * 3072, 3072, 3072, 512);
}